// Round 2
// baseline (1154.698 us; speedup 1.0000x reference)
//
#include <hip/hip_runtime.h>
#include <hip/hip_bf16.h>
#include <math.h>

// Problem constants: B=4, T=512, I=128, H=128 (4H=512)
#define Bq 4
#define Tq 512
#define Hq 128

typedef _Float16 f16x8 __attribute__((ext_vector_type(8)));
typedef float f32x4 __attribute__((ext_vector_type(4)));

__device__ __forceinline__ float sigmoid_fast(float x) {
    return 1.0f / (1.0f + __expf(-x));
}
__device__ __forceinline__ float tanh_fast(float x) {
    // tanh(x) = 1 - 2/(exp(2x)+1); saturates correctly for |x| large
    float e = __expf(2.0f * x);
    return 1.0f - 2.0f / (e + 1.0f);
}

// ---------------------------------------------------------------------------
// GEMM "nt": C[m,n] = sum_k A[m,k] * W[n,k] (+bias[n]) (+= C)   K=128 fixed
// A: [2048, lda>=128], W rows stride ldw, C: [2048, 512] (ldc=512)
// grid (32, 8), block 256
// ---------------------------------------------------------------------------
__global__ __launch_bounds__(256) void gemm_nt(const float* __restrict__ A, int lda,
                                               const float* __restrict__ W, int ldw,
                                               const float* __restrict__ bias,
                                               float* __restrict__ C, int acc_flag) {
    __shared__ __align__(16) float As[64][68];
    __shared__ __align__(16) float Ws[64][68];
    int m0 = blockIdx.x * 64, n0 = blockIdx.y * 64;
    int tid = threadIdx.x;
    int tx = tid & 15, ty = tid >> 4;
    float acc[4][4] = {};
    for (int kc = 0; kc < 2; kc++) {
        __syncthreads();
#pragma unroll
        for (int i = 0; i < 4; i++) {
            int idx = tid + 256 * i;
            int r = idx >> 4, c4 = idx & 15;
            *(float4*)(&As[r][c4 * 4]) = *(const float4*)(A + (size_t)(m0 + r) * lda + kc * 64 + c4 * 4);
            *(float4*)(&Ws[r][c4 * 4]) = *(const float4*)(W + (size_t)(n0 + r) * ldw + kc * 64 + c4 * 4);
        }
        __syncthreads();
#pragma unroll
        for (int k4 = 0; k4 < 16; k4++) {
            float4 a[4], wv[4];
#pragma unroll
            for (int i = 0; i < 4; i++) a[i] = *(const float4*)(&As[ty * 4 + i][k4 * 4]);
#pragma unroll
            for (int j = 0; j < 4; j++) wv[j] = *(const float4*)(&Ws[tx * 4 + j][k4 * 4]);
#pragma unroll
            for (int i = 0; i < 4; i++)
#pragma unroll
                for (int j = 0; j < 4; j++)
                    acc[i][j] += a[i].x * wv[j].x + a[i].y * wv[j].y + a[i].z * wv[j].z + a[i].w * wv[j].w;
        }
    }
#pragma unroll
    for (int i = 0; i < 4; i++) {
        int m = m0 + ty * 4 + i;
        int n = n0 + tx * 4;
        float4 v = make_float4(acc[i][0], acc[i][1], acc[i][2], acc[i][3]);
        if (bias) { v.x += bias[n]; v.y += bias[n + 1]; v.z += bias[n + 2]; v.w += bias[n + 3]; }
        if (acc_flag) {
            float4 o = *(const float4*)(C + (size_t)m * 512 + n);
            v.x += o.x; v.y += o.y; v.z += o.z; v.w += o.w;
        }
        *(float4*)(C + (size_t)m * 512 + n) = v;
    }
}

// ---------------------------------------------------------------------------
// GEMM "nn" (dual-A fused): C[m,n] = sum_k A1[m,k]B1[k,n] (+ sum_k A2[m,k]B2[k,n]) + bias
// A: [2048,128]; B: [128,128]; C: [2048,128].  grid (32, 2), block 256
// ---------------------------------------------------------------------------
__global__ __launch_bounds__(256) void gemm_nn(const float* __restrict__ A1, const float* __restrict__ B1,
                                               const float* __restrict__ A2, const float* __restrict__ B2,
                                               const float* __restrict__ bias,
                                               float* __restrict__ C) {
    __shared__ __align__(16) float As[64][68];
    __shared__ __align__(16) float Bs[64][68];
    int m0 = blockIdx.x * 64, n0 = blockIdx.y * 64;
    int tid = threadIdx.x;
    int tx = tid & 15, ty = tid >> 4;
    float acc[4][4] = {};
    for (int src = 0; src < 2; src++) {
        const float* A = src ? A2 : A1;
        const float* Bm = src ? B2 : B1;
        if (!A) break;
        for (int kc = 0; kc < 2; kc++) {
            __syncthreads();
#pragma unroll
            for (int i = 0; i < 4; i++) {
                int idx = tid + 256 * i;
                int r = idx >> 4, c4 = idx & 15;
                *(float4*)(&As[r][c4 * 4]) = *(const float4*)(A + (size_t)(m0 + r) * 128 + kc * 64 + c4 * 4);
                *(float4*)(&Bs[r][c4 * 4]) = *(const float4*)(Bm + (size_t)(kc * 64 + r) * 128 + n0 + c4 * 4);
            }
            __syncthreads();
#pragma unroll
            for (int k4 = 0; k4 < 16; k4++) {
                float4 a[4];
#pragma unroll
                for (int i = 0; i < 4; i++) a[i] = *(const float4*)(&As[ty * 4 + i][k4 * 4]);
#pragma unroll
                for (int kk = 0; kk < 4; kk++) {
                    float4 bv = *(const float4*)(&Bs[k4 * 4 + kk][tx * 4]);
#pragma unroll
                    for (int i = 0; i < 4; i++) {
                        float av = (kk == 0) ? a[i].x : (kk == 1) ? a[i].y : (kk == 2) ? a[i].z : a[i].w;
                        acc[i][0] += av * bv.x;
                        acc[i][1] += av * bv.y;
                        acc[i][2] += av * bv.z;
                        acc[i][3] += av * bv.w;
                    }
                }
            }
        }
    }
#pragma unroll
    for (int i = 0; i < 4; i++) {
        int m = m0 + ty * 4 + i;
        int n = n0 + tx * 4;
        float4 v = make_float4(acc[i][0], acc[i][1], acc[i][2], acc[i][3]);
        if (bias) { v.x += bias[n]; v.y += bias[n + 1]; v.z += bias[n + 2]; v.w += bias[n + 3]; }
        *(float4*)(C + (size_t)m * 128 + n) = v;
    }
}

// ---------------------------------------------------------------------------
// MFMA LSTM recurrence. grid = B blocks (1 CU/chain), block = 512 (8 waves).
// Wave w owns gate columns [16w,16w+16) of ALL FOUR gates: MFMA N-tiles at
// n0 = g*128 + 16w. With C layout col=lane&15,row=(lane>>4)*4+reg, lane l<16
// holds i,f,g,o preacts for channel 16w+l in acc[g][0] -> no gate exchange,
// no reduction, c stays in-register. M=16 tile: batch = row 0, rows 1-15
// read zeros from LDS. h ping-pongs in LDS as f16 (XOR-swizzled chunks).
// One lean barrier/step (lgkmcnt only -- Hout stores never drained).
// ---------------------------------------------------------------------------
__global__ __launch_bounds__(512) void lstm_mfma(const float* __restrict__ xg,
                                                 const float* __restrict__ Whh,
                                                 float* __restrict__ Hout) {
    int b = blockIdx.x;
    int tid = threadIdx.x;
    int w = tid >> 6, lane = tid & 63;
    int row = lane & 15, kgrp = lane >> 4;
    int chan = 16 * w + row;

    // h buffers: [2][16 rows][128 ch] f16, chunk-swizzled: elem(r,k) at
    // r*128 + ((k>>3 ^ r)<<3) + (k&7). Row 0 real, rows 1-15 stay zero.
    __shared__ _Float16 hbuf[2][2048];

    for (int i = tid; i < 4096; i += 512) (&hbuf[0][0])[i] = (_Float16)0.f;

    // B fragments (registers-stationary): B[k][n]=Whh[n][k];
    // lane l: col = n0 + (l&15), k = kb*32 + (l>>4)*8 + j
    f16x8 Bf[4][4];
#pragma unroll
    for (int g = 0; g < 4; g++) {
        const float* wr = Whh + (size_t)(g * 128 + chan) * 128;
#pragma unroll
        for (int kb = 0; kb < 4; kb++) {
            int k0 = kb * 32 + kgrp * 8;
            float4 lo = *(const float4*)(wr + k0);
            float4 hi = *(const float4*)(wr + k0 + 4);
            f16x8 v;
            v[0] = (_Float16)lo.x; v[1] = (_Float16)lo.y;
            v[2] = (_Float16)lo.z; v[3] = (_Float16)lo.w;
            v[4] = (_Float16)hi.x; v[5] = (_Float16)hi.y;
            v[6] = (_Float16)hi.z; v[7] = (_Float16)hi.w;
            Bf[g][kb] = v;
        }
    }

    const float* xgb = xg + (size_t)b * Tq * 512;
    float xc0 = 0.f, xc1 = 0.f, xc2 = 0.f, xc3 = 0.f;
    if (lane < 16) {
        xc0 = xgb[0 * 128 + chan];
        xc1 = xgb[1 * 128 + chan];
        xc2 = xgb[2 * 128 + chan];
        xc3 = xgb[3 * 128 + chan];
    }
    float c = 0.f;
    int p = 0;
    __syncthreads();

    for (int t = 0; t < Tq; t++) {
        // init accumulators: row 0 (reg 0, lanes<16) = xg, rest 0
        f32x4 acc[4];
#pragma unroll
        for (int g = 0; g < 4; g++) {
            float x0 = (g == 0) ? xc0 : (g == 1) ? xc1 : (g == 2) ? xc2 : xc3;
            acc[g][0] = (lane < 16) ? x0 : 0.f;
            acc[g][1] = 0.f; acc[g][2] = 0.f; acc[g][3] = 0.f;
        }
        // prefetch next step's xg (latency hidden under MFMAs)
        {
            int tn = (t < Tq - 1) ? t + 1 : t;
            if (lane < 16) {
                const float* px = xgb + (size_t)tn * 512 + chan;
                xc0 = px[0]; xc1 = px[128]; xc2 = px[256]; xc3 = px[384];
            }
        }
        // A fragments: lane l reads h[row=l&15][kb*32 + (l>>4)*8 .. +8]
        f16x8 Af[4];
#pragma unroll
        for (int kb = 0; kb < 4; kb++) {
            int chunk = (kb * 4 + kgrp) ^ row;
            Af[kb] = *(const f16x8*)&hbuf[p][row * 128 + chunk * 8];
        }
#pragma unroll
        for (int kb = 0; kb < 4; kb++) {
#pragma unroll
            for (int g = 0; g < 4; g++) {
                acc[g] = __builtin_amdgcn_mfma_f32_16x16x32_f16(Af[kb], Bf[g][kb], acc[g], 0, 0, 0);
            }
        }
        // gate update: lane l<16 owns (batch b, channel 16w+l); others compute
        // harmless zeros. c stays in-register.
        float gi = acc[0][0], gf = acc[1][0], gg = acc[2][0], go = acc[3][0];
        float si = sigmoid_fast(gi), sf = sigmoid_fast(gf), so = sigmoid_fast(go);
        float tg = tanh_fast(gg);
        c = sf * c + si * tg;
        float h = so * tanh_fast(c);
        if (lane < 16) {
            hbuf[p ^ 1][chan] = (_Float16)h;   // row 0, swizzle identity
            Hout[((size_t)b * Tq + t) * Hq + chan] = h;
        }
        // lean barrier: wait LDS ops only; global stores/loads stay in flight
        asm volatile("s_waitcnt lgkmcnt(0)\n\ts_barrier" ::: "memory");
        p ^= 1;
    }
}

// ---------------------------------------------------------------------------
// Attention: per (t,b) block: scores_s = u . tanh(a_t + c_s), softmax over s,
// R[b,t,:] = sum_s beta_s * Hsh[b,s,:].  (bu omitted: softmax-invariant)
// grid (T, B), block 256
// ---------------------------------------------------------------------------
__global__ __launch_bounds__(256) void attn_kernel(const float* __restrict__ hp_t,
                                                   const float* __restrict__ c_s,
                                                   const float* __restrict__ u,
                                                   const float* __restrict__ Hsh,
                                                   float* __restrict__ R) {
    int t = blockIdx.x, b = blockIdx.y;
    int tid = threadIdx.x;
    __shared__ __align__(16) float a_lds[128];
    __shared__ __align__(16) float u_lds[128];
    __shared__ __align__(16) float sc[512];
    __shared__ __align__(16) float red[256];

    if (tid < 128) {
        a_lds[tid] = hp_t[((size_t)b * Tq + t) * Hq + tid];
        u_lds[tid] = u[tid];
    }
    __syncthreads();

#pragma unroll
    for (int r = 0; r < 2; r++) {
        int s = tid + 256 * r;
        const float4* crow = (const float4*)(c_s + ((size_t)b * Tq + s) * Hq);
        float acc = 0.0f;
#pragma unroll 8
        for (int h4 = 0; h4 < 32; h4++) {
            float4 cv = crow[h4];
            float4 av = *(const float4*)(&a_lds[h4 * 4]);
            float4 uv = *(const float4*)(&u_lds[h4 * 4]);
            acc += uv.x * tanh_fast(av.x + cv.x) + uv.y * tanh_fast(av.y + cv.y)
                 + uv.z * tanh_fast(av.z + cv.z) + uv.w * tanh_fast(av.w + cv.w);
        }
        sc[s] = acc;
    }
    __syncthreads();

    float m = fmaxf(sc[tid], sc[tid + 256]);
    red[tid] = m;
    __syncthreads();
    for (int off = 128; off > 0; off >>= 1) {
        if (tid < off) red[tid] = fmaxf(red[tid], red[tid + off]);
        __syncthreads();
    }
    m = red[0];
    __syncthreads();

    float p0 = __expf(sc[tid] - m), p1 = __expf(sc[tid + 256] - m);
    sc[tid] = p0; sc[tid + 256] = p1;
    red[tid] = p0 + p1;
    __syncthreads();
    for (int off = 128; off > 0; off >>= 1) {
        if (tid < off) red[tid] += red[tid + off];
        __syncthreads();
    }
    float rinv = 1.0f / red[0];
    __syncthreads();

    int h = tid & 127, half = tid >> 7;
    float acc = 0.0f;
    for (int s = half; s < 512; s += 2) {
        acc += sc[s] * Hsh[((size_t)b * Tq + s) * Hq + h];
    }
    red[tid] = acc;
    __syncthreads();
    if (tid < 128) {
        R[((size_t)b * Tq + t) * Hq + tid] = (red[tid] + red[tid + 128]) * rinv;
    }
}

// ---------------------------------------------------------------------------
extern "C" void kernel_launch(void* const* d_in, const int* in_sizes, int n_in,
                              void* d_out, int out_size, void* d_ws, size_t ws_size,
                              hipStream_t stream) {
    const float* x      = (const float*)d_in[0];
    const float* Wih_s  = (const float*)d_in[1];
    const float* Whh_s  = (const float*)d_in[2];
    const float* b_s    = (const float*)d_in[3];
    const float* Wx     = (const float*)d_in[4];
    const float* Wht    = (const float*)d_in[5];
    const float* Whs    = (const float*)d_in[6];
    const float* bs     = (const float*)d_in[7];
    const float* u      = (const float*)d_in[8];
    // d_in[9] = bu: constant shift of scores -> softmax-invariant, unused
    const float* Wih_t  = (const float*)d_in[10];
    const float* Whh_t  = (const float*)d_in[11];
    const float* b_t    = (const float*)d_in[12];
    float* out = (float*)d_out;

    // workspace layout (floats)
    float* ws    = (float*)d_ws;
    float* xg_s  = ws;                 // [B,T,512]
    float* xg_t  = ws + 1048576;       // [B,T,512]
    float* Hsh   = ws + 2097152;       // [B,T,128]
    float* hp_t  = ws + 2359296;       // [B,T,128]
    float* c_s   = ws + 2621440;       // [B,T,128]
    float* Rbuf  = ws + 2883584;       // [B,T,128]

    dim3 blk(256);
    dim3 g_nt(32, 8);
    dim3 g_nn(32, 2);

    // 1) input projections for both LSTMs
    gemm_nt<<<g_nt, blk, 0, stream>>>(x, 128, Wih_s, 128, b_s, xg_s, 0);
    gemm_nt<<<g_nt, blk, 0, stream>>>(x, 128, Wih_t, 256, b_t, xg_t, 0);

    // 2) shared LSTM
    lstm_mfma<<<Bq, 512, 0, stream>>>(xg_s, Whh_s, Hsh);

    // 3) attention precursors: hp_t = Hsh@Wht ; c_s = x@Wx + Hsh@Whs + bs
    gemm_nn<<<g_nn, blk, 0, stream>>>(Hsh, Wht, nullptr, nullptr, nullptr, hp_t);
    gemm_nn<<<g_nn, blk, 0, stream>>>(x, Wx, Hsh, Whs, bs, c_s);

    // 4) attention scores + softmax + weighted sum
    attn_kernel<<<dim3(Tq, Bq), blk, 0, stream>>>(hp_t, c_s, u, Hsh, Rbuf);

    // 5) add R projection into task-LSTM input gates: xg_t += R @ Wih_t[:,128:].T
    gemm_nt<<<g_nt, blk, 0, stream>>>(Rbuf, 128, Wih_t + 128, 256, nullptr, xg_t, 1);

    // 6) task LSTM -> output
    lstm_mfma<<<Bq, 512, 0, stream>>>(xg_t, Whh_t, out);
}

// Round 3
// 853.223 us; speedup vs baseline: 1.3533x; 1.3533x over previous
//
#include <hip/hip_runtime.h>
#include <hip/hip_bf16.h>
#include <math.h>

// Problem constants: B=4, T=512, I=128, H=128 (4H=512)
#define Bq 4
#define Tq 512
#define Hq 128

typedef _Float16 h2_t __attribute__((ext_vector_type(2)));
typedef _Float16 f16x8 __attribute__((ext_vector_type(8)));

__device__ __forceinline__ float sigmoid_fast(float x) {
    return 1.0f / (1.0f + __expf(-x));
}
__device__ __forceinline__ float tanh_fast(float x) {
    // tanh(x) = 1 - 2/(exp(2x)+1); saturates correctly for |x| large
    float e = __expf(2.0f * x);
    return 1.0f - 2.0f / (e + 1.0f);
}

// ---------------------------------------------------------------------------
// GEMM "nt": C[m,n] = sum_k A[m,k] * W[n,k] (+bias[n]) (+= C)   K=128 fixed
// A: [2048, lda>=128], W rows stride ldw, C: [2048, 512] (ldc=512)
// grid (32, 8), block 256
// ---------------------------------------------------------------------------
__global__ __launch_bounds__(256) void gemm_nt(const float* __restrict__ A, int lda,
                                               const float* __restrict__ W, int ldw,
                                               const float* __restrict__ bias,
                                               float* __restrict__ C, int acc_flag) {
    __shared__ __align__(16) float As[64][68];
    __shared__ __align__(16) float Ws[64][68];
    int m0 = blockIdx.x * 64, n0 = blockIdx.y * 64;
    int tid = threadIdx.x;
    int tx = tid & 15, ty = tid >> 4;
    float acc[4][4] = {};
    for (int kc = 0; kc < 2; kc++) {
        __syncthreads();
#pragma unroll
        for (int i = 0; i < 4; i++) {
            int idx = tid + 256 * i;
            int r = idx >> 4, c4 = idx & 15;
            *(float4*)(&As[r][c4 * 4]) = *(const float4*)(A + (size_t)(m0 + r) * lda + kc * 64 + c4 * 4);
            *(float4*)(&Ws[r][c4 * 4]) = *(const float4*)(W + (size_t)(n0 + r) * ldw + kc * 64 + c4 * 4);
        }
        __syncthreads();
#pragma unroll
        for (int k4 = 0; k4 < 16; k4++) {
            float4 a[4], wv[4];
#pragma unroll
            for (int i = 0; i < 4; i++) a[i] = *(const float4*)(&As[ty * 4 + i][k4 * 4]);
#pragma unroll
            for (int j = 0; j < 4; j++) wv[j] = *(const float4*)(&Ws[tx * 4 + j][k4 * 4]);
#pragma unroll
            for (int i = 0; i < 4; i++)
#pragma unroll
                for (int j = 0; j < 4; j++)
                    acc[i][j] += a[i].x * wv[j].x + a[i].y * wv[j].y + a[i].z * wv[j].z + a[i].w * wv[j].w;
        }
    }
#pragma unroll
    for (int i = 0; i < 4; i++) {
        int m = m0 + ty * 4 + i;
        int n = n0 + tx * 4;
        float4 v = make_float4(acc[i][0], acc[i][1], acc[i][2], acc[i][3]);
        if (bias) { v.x += bias[n]; v.y += bias[n + 1]; v.z += bias[n + 2]; v.w += bias[n + 3]; }
        if (acc_flag) {
            float4 o = *(const float4*)(C + (size_t)m * 512 + n);
            v.x += o.x; v.y += o.y; v.z += o.z; v.w += o.w;
        }
        *(float4*)(C + (size_t)m * 512 + n) = v;
    }
}

// ---------------------------------------------------------------------------
// GEMM "nn" (dual-A fused): C[m,n] = sum_k A1[m,k]B1[k,n] (+ sum_k A2[m,k]B2[k,n]) + bias
// A: [2048,128]; B: [128,128]; C: [2048,128].  grid (32, 2), block 256
// ---------------------------------------------------------------------------
__global__ __launch_bounds__(256) void gemm_nn(const float* __restrict__ A1, const float* __restrict__ B1,
                                               const float* __restrict__ A2, const float* __restrict__ B2,
                                               const float* __restrict__ bias,
                                               float* __restrict__ C) {
    __shared__ __align__(16) float As[64][68];
    __shared__ __align__(16) float Bs[64][68];
    int m0 = blockIdx.x * 64, n0 = blockIdx.y * 64;
    int tid = threadIdx.x;
    int tx = tid & 15, ty = tid >> 4;
    float acc[4][4] = {};
    for (int src = 0; src < 2; src++) {
        const float* A = src ? A2 : A1;
        const float* Bm = src ? B2 : B1;
        if (!A) break;
        for (int kc = 0; kc < 2; kc++) {
            __syncthreads();
#pragma unroll
            for (int i = 0; i < 4; i++) {
                int idx = tid + 256 * i;
                int r = idx >> 4, c4 = idx & 15;
                *(float4*)(&As[r][c4 * 4]) = *(const float4*)(A + (size_t)(m0 + r) * 128 + kc * 64 + c4 * 4);
                *(float4*)(&Bs[r][c4 * 4]) = *(const float4*)(Bm + (size_t)(kc * 64 + r) * 128 + n0 + c4 * 4);
            }
            __syncthreads();
#pragma unroll
            for (int k4 = 0; k4 < 16; k4++) {
                float4 a[4];
#pragma unroll
                for (int i = 0; i < 4; i++) a[i] = *(const float4*)(&As[ty * 4 + i][k4 * 4]);
#pragma unroll
                for (int kk = 0; kk < 4; kk++) {
                    float4 bv = *(const float4*)(&Bs[k4 * 4 + kk][tx * 4]);
#pragma unroll
                    for (int i = 0; i < 4; i++) {
                        float av = (kk == 0) ? a[i].x : (kk == 1) ? a[i].y : (kk == 2) ? a[i].z : a[i].w;
                        acc[i][0] += av * bv.x;
                        acc[i][1] += av * bv.y;
                        acc[i][2] += av * bv.z;
                        acc[i][3] += av * bv.w;
                    }
                }
            }
        }
    }
#pragma unroll
    for (int i = 0; i < 4; i++) {
        int m = m0 + ty * 4 + i;
        int n = n0 + tx * 4;
        float4 v = make_float4(acc[i][0], acc[i][1], acc[i][2], acc[i][3]);
        if (bias) { v.x += bias[n]; v.y += bias[n + 1]; v.z += bias[n + 2]; v.w += bias[n + 3]; }
        *(float4*)(C + (size_t)m * 128 + n) = v;
    }
}

// ---------------------------------------------------------------------------
// dot2 LSTM recurrence. grid = B blocks (1 CU/chain), block = 256 (4 waves,
// one per SIMD). Wave w owns channels [32w, 32w+32); lane = (ch, khalf):
// ch = 32w + (lane&31), kh = lane>>5. Per lane: all 4 gate rows of its
// channel over its 64-k half, as f16 half2 in VGPRs (128 VGPR, stationary).
// matvec: 128 v_dot2_f32_f16 per lane (issue floor 256 cyc/SIMD).
// k-half reduce: 4x shfl_xor(32) in-wave (no LDS round trip, no 2nd barrier).
// i,f,g,o of a channel land in one lane -> c stays in-register.
// h ping-pongs in LDS as f16 (512 B); ONE lean barrier per step
// (lgkmcnt only -- Hout stores + xg prefetch loads stay in flight).
// xg for step t+1 prefetched during step t (full step of latency slack).
// ---------------------------------------------------------------------------
__global__ __launch_bounds__(256, 1) void lstm_dot2(const float* __restrict__ xg,
                                                    const float* __restrict__ Whh,
                                                    float* __restrict__ Hout) {
    int b = blockIdx.x;
    int tid = threadIdx.x;
    int lane = tid & 63;
    int w = tid >> 6;
    int ch = 32 * w + (lane & 31);
    int kh = lane >> 5;

    __shared__ _Float16 hbuf[2][128];
    if (tid < 256) (&hbuf[0][0])[tid] = (_Float16)0.f;

    // stationary weights: w2[g][k2] = Whh[g*128+ch][kh*64 + 2*k2 .. +1] as half2
    h2_t w2[4][32];
#pragma unroll
    for (int g = 0; g < 4; g++) {
        const float* wr = Whh + (size_t)(g * 128 + ch) * 128 + kh * 64;
#pragma unroll
        for (int k2 = 0; k2 < 32; k2++) {
            float2 v = *(const float2*)(wr + 2 * k2);
            h2_t p; p[0] = (_Float16)v.x; p[1] = (_Float16)v.y;
            w2[g][k2] = p;
        }
    }

    const float* xgb = xg + (size_t)b * Tq * 512;
    // prologue: xg for t=0 (all lanes load; kh halves redundant but harmless)
    float xc0 = xgb[0 * 128 + ch];
    float xc1 = xgb[1 * 128 + ch];
    float xc2 = xgb[2 * 128 + ch];
    float xc3 = xgb[3 * 128 + ch];

    float c = 0.f;
    int p = 0;
    __syncthreads();

    for (int t = 0; t < Tq; t++) {
        // h fragment: this lane's 64-k half (broadcast reads, conflict-free)
        f16x8 hv[8];
        const f16x8* hb = (const f16x8*)(&hbuf[p][kh * 64]);
#pragma unroll
        for (int i = 0; i < 8; i++) hv[i] = hb[i];

        // prefetch next step's xg early: consumed AFTER next barrier,
        // a full step of slack hides global latency.
        int tn = (t < Tq - 1) ? t + 1 : t;
        const float* px = xgb + (size_t)tn * 512 + ch;
        float nxc0 = px[0], nxc1 = px[128], nxc2 = px[256], nxc3 = px[384];

        // matvec: 4 independent acc chains, 128 dot2 total
        float acc0 = 0.f, acc1 = 0.f, acc2 = 0.f, acc3 = 0.f;
        const h2_t* h2 = (const h2_t*)hv;
#pragma unroll
        for (int k2 = 0; k2 < 32; k2++) {
            h2_t hh = h2[k2];
            acc0 = __builtin_amdgcn_fdot2(hh, w2[0][k2], acc0, false);
            acc1 = __builtin_amdgcn_fdot2(hh, w2[1][k2], acc1, false);
            acc2 = __builtin_amdgcn_fdot2(hh, w2[2][k2], acc2, false);
            acc3 = __builtin_amdgcn_fdot2(hh, w2[3][k2], acc3, false);
        }
        // k-half reduce in-wave; both halves end with full sums (redundant)
        acc0 += __shfl_xor(acc0, 32, 64);
        acc1 += __shfl_xor(acc1, 32, 64);
        acc2 += __shfl_xor(acc2, 32, 64);
        acc3 += __shfl_xor(acc3, 32, 64);

        // gate math (redundant across kh halves; c consistent in both)
        float gi = acc0 + xc0, gf = acc1 + xc1, gg = acc2 + xc2, go = acc3 + xc3;
        float si = sigmoid_fast(gi), sf = sigmoid_fast(gf), so = sigmoid_fast(go);
        float tg = tanh_fast(gg);
        c = sf * c + si * tg;
        float h = so * tanh_fast(c);

        if (lane < 32) {
            hbuf[p ^ 1][ch] = (_Float16)h;
            Hout[((size_t)b * Tq + t) * Hq + ch] = h;
        }
        // lean barrier: wait LDS ops only; global stores/loads stay in flight
        asm volatile("s_waitcnt lgkmcnt(0)\n\ts_barrier" ::: "memory");
        xc0 = nxc0; xc1 = nxc1; xc2 = nxc2; xc3 = nxc3;
        p ^= 1;
    }
}

// ---------------------------------------------------------------------------
// Attention: per (t,b) block: scores_s = u . tanh(a_t + c_s), softmax over s,
// R[b,t,:] = sum_s beta_s * Hsh[b,s,:].  (bu omitted: softmax-invariant)
// grid (T, B), block 256
// ---------------------------------------------------------------------------
__global__ __launch_bounds__(256) void attn_kernel(const float* __restrict__ hp_t,
                                                   const float* __restrict__ c_s,
                                                   const float* __restrict__ u,
                                                   const float* __restrict__ Hsh,
                                                   float* __restrict__ R) {
    int t = blockIdx.x, b = blockIdx.y;
    int tid = threadIdx.x;
    __shared__ __align__(16) float a_lds[128];
    __shared__ __align__(16) float u_lds[128];
    __shared__ __align__(16) float sc[512];
    __shared__ __align__(16) float red[256];

    if (tid < 128) {
        a_lds[tid] = hp_t[((size_t)b * Tq + t) * Hq + tid];
        u_lds[tid] = u[tid];
    }
    __syncthreads();

#pragma unroll
    for (int r = 0; r < 2; r++) {
        int s = tid + 256 * r;
        const float4* crow = (const float4*)(c_s + ((size_t)b * Tq + s) * Hq);
        float acc = 0.0f;
#pragma unroll 8
        for (int h4 = 0; h4 < 32; h4++) {
            float4 cv = crow[h4];
            float4 av = *(const float4*)(&a_lds[h4 * 4]);
            float4 uv = *(const float4*)(&u_lds[h4 * 4]);
            acc += uv.x * tanh_fast(av.x + cv.x) + uv.y * tanh_fast(av.y + cv.y)
                 + uv.z * tanh_fast(av.z + cv.z) + uv.w * tanh_fast(av.w + cv.w);
        }
        sc[s] = acc;
    }
    __syncthreads();

    float m = fmaxf(sc[tid], sc[tid + 256]);
    red[tid] = m;
    __syncthreads();
    for (int off = 128; off > 0; off >>= 1) {
        if (tid < off) red[tid] = fmaxf(red[tid], red[tid + off]);
        __syncthreads();
    }
    m = red[0];
    __syncthreads();

    float p0 = __expf(sc[tid] - m), p1 = __expf(sc[tid + 256] - m);
    sc[tid] = p0; sc[tid + 256] = p1;
    red[tid] = p0 + p1;
    __syncthreads();
    for (int off = 128; off > 0; off >>= 1) {
        if (tid < off) red[tid] += red[tid + off];
        __syncthreads();
    }
    float rinv = 1.0f / red[0];
    __syncthreads();

    int h = tid & 127, half = tid >> 7;
    float acc = 0.0f;
    for (int s = half; s < 512; s += 2) {
        acc += sc[s] * Hsh[((size_t)b * Tq + s) * Hq + h];
    }
    red[tid] = acc;
    __syncthreads();
    if (tid < 128) {
        R[((size_t)b * Tq + t) * Hq + tid] = (red[tid] + red[tid + 128]) * rinv;
    }
}

// ---------------------------------------------------------------------------
extern "C" void kernel_launch(void* const* d_in, const int* in_sizes, int n_in,
                              void* d_out, int out_size, void* d_ws, size_t ws_size,
                              hipStream_t stream) {
    const float* x      = (const float*)d_in[0];
    const float* Wih_s  = (const float*)d_in[1];
    const float* Whh_s  = (const float*)d_in[2];
    const float* b_s    = (const float*)d_in[3];
    const float* Wx     = (const float*)d_in[4];
    const float* Wht    = (const float*)d_in[5];
    const float* Whs    = (const float*)d_in[6];
    const float* bs     = (const float*)d_in[7];
    const float* u      = (const float*)d_in[8];
    // d_in[9] = bu: constant shift of scores -> softmax-invariant, unused
    const float* Wih_t  = (const float*)d_in[10];
    const float* Whh_t  = (const float*)d_in[11];
    const float* b_t    = (const float*)d_in[12];
    float* out = (float*)d_out;

    // workspace layout (floats)
    float* ws    = (float*)d_ws;
    float* xg_s  = ws;                 // [B,T,512]
    float* xg_t  = ws + 1048576;       // [B,T,512]
    float* Hsh   = ws + 2097152;       // [B,T,128]
    float* hp_t  = ws + 2359296;       // [B,T,128]
    float* c_s   = ws + 2621440;       // [B,T,128]
    float* Rbuf  = ws + 2883584;       // [B,T,128]

    dim3 blk(256);
    dim3 g_nt(32, 8);
    dim3 g_nn(32, 2);

    // 1) input projections for both LSTMs
    gemm_nt<<<g_nt, blk, 0, stream>>>(x, 128, Wih_s, 128, b_s, xg_s, 0);
    gemm_nt<<<g_nt, blk, 0, stream>>>(x, 128, Wih_t, 256, b_t, xg_t, 0);

    // 2) shared LSTM
    lstm_dot2<<<Bq, 256, 0, stream>>>(xg_s, Whh_s, Hsh);

    // 3) attention precursors: hp_t = Hsh@Wht ; c_s = x@Wx + Hsh@Whs + bs
    gemm_nn<<<g_nn, blk, 0, stream>>>(Hsh, Wht, nullptr, nullptr, nullptr, hp_t);
    gemm_nn<<<g_nn, blk, 0, stream>>>(x, Wx, Hsh, Whs, bs, c_s);

    // 4) attention scores + softmax + weighted sum
    attn_kernel<<<dim3(Tq, Bq), blk, 0, stream>>>(hp_t, c_s, u, Hsh, Rbuf);

    // 5) add R projection into task-LSTM input gates: xg_t += R @ Wih_t[:,128:].T
    gemm_nt<<<g_nt, blk, 0, stream>>>(Rbuf, 128, Wih_t + 128, 256, nullptr, xg_t, 1);

    // 6) task LSTM -> output
    lstm_dot2<<<Bq, 256, 0, stream>>>(xg_t, Whh_t, out);
}